// Round 13
// baseline (8949.322 us; speedup 1.0000x reference)
//
#include <hip/hip_runtime.h>

// SpikeMLP — R24: wave-uniform A (LDS broadcast) + W-only full-BW LDS.
// Chain contract (FROZEN, verified absmax=0.0 @ R14-R16,R18-R23):
//   per C element: acc = fma(a_k, w_k, acc), k = 0..1023 strictly
//   ascending, single accumulator, fp32, contract off. Recurrence fp32
//   ufunc order. MFMA / k-reassociation / packed-fp32 forbidden (R22:
//   v_pk_fma_f32 is half-rate; R21 scalar is the keeper).
// DS-pipe model (m134, explains R14-R23 plateau at ~1600us/GEMM):
//   R21 inner kk: 4 full-BW ds_read_b128/wave x4 waves = 192 DS-cyc per
//   128 VALU-cyc -> DS 1.5x oversubscribed. R24 remap: wave owns 8
//   m-rows x 256 n (lane = 4 cols) ->
//     W: 1 ds_read_b128/lane/kk (12cyc); A: 2 wave-uniform broadcast
//     b128 (~4cyc, 16B); DS/CU/kk ~80 vs 64 VALU (bytes: 66 < 85 cap).
//   W from k-major Wt (transp kernel, scratch in d_out — R18-proven).
//   LDS 36KB -> 4 blocks/CU; VGPR ~90, __launch_bounds__(256,4).
// Predicted: VGPR ~90-110, WRITE 262MB (jump => spill => abort-read),
//   Occ ~50%, VALUBusy 85-90%, big GEMM ~1050-1250us, total ~2.7-3.0ms,
//   absmax 0.0. Flat => broadcast not cheap => next: s_load asm for A.

typedef float floatx4 __attribute__((ext_vector_type(4)));

static constexpr int BSZ   = 4096;
static constexpr int D_IN  = 1024;
static constexpr int H1    = 1024;
static constexpr int D_OUT = 512;
static constexpr int M_ROWS = BSZ * 16;   // 65536, m = b*16 + t

// ---------------------------------------------------------------------------
// pack X [B, D_in, T=16] f32 -> A [m = b*16 + t][d] f32 (spikes exactly 0/1)
// ---------------------------------------------------------------------------
__global__ void pack_x(const float* __restrict__ X, float* __restrict__ A) {
    const int P = blockIdx.x * 256 + threadIdx.x;     // P = b*1024 + d
    const int b = P >> 10, d = P & 1023;
    const float4* xp = (const float4*)(X + (size_t)P * 16);
    float4 x0 = xp[0], x1 = xp[1], x2 = xp[2], x3 = xp[3];
    const float v[16] = {x0.x, x0.y, x0.z, x0.w, x1.x, x1.y, x1.z, x1.w,
                         x2.x, x2.y, x2.z, x2.w, x3.x, x3.y, x3.z, x3.w};
#pragma unroll
    for (int t = 0; t < 16; ++t)
        A[((size_t)(b * 16 + t)) * 1024 + d] = v[t];
}

// ---------------------------------------------------------------------------
// W [R][1024] -> Wt [1024][R]  (pure copy, bit-exact)
// ---------------------------------------------------------------------------
__global__ void transp(const float* __restrict__ W, float* __restrict__ Wt,
                       int R) {
    const int P = blockIdx.x * 256 + threadIdx.x;   // n*1024 + k
    const int k = P & 1023, n = P >> 10;
    Wt[(size_t)k * R + n] = W[P];
}

// ---------------------------------------------------------------------------
// GEMM, reference fp32 chain. C[m][n] = A[m,:] . W[n,:], K = 1024.
// Block: 32 m (4 waves x 8 rows) x 256 n. Lane tile 8m x 4n (32 acc).
// BK = 32. LDS: Ws[32][256] k-major (full-BW reads), As[32][32] k-major
// (wave-uniform broadcast reads). Two barriers per tile.
// Single ascending accumulator over full K (frozen chain).
// ---------------------------------------------------------------------------
__global__ __launch_bounds__(256, 4) void gemm_np(
    const float* __restrict__ A,    // [M, 1024] f32 spikes (exactly 0/1)
    const float* __restrict__ Wt,   // [1024, N] f32 (k-major transpose of W)
    float* __restrict__ C,          // [M, N] fp32
    int N) {
#pragma clang fp contract(off)
    __shared__ float Ws[32][256];   // [kk][n]  32 KB
    __shared__ float As[32][32];    // [kk][m]   4 KB

    const int tid  = threadIdx.x;
    const int lane = tid & 63;
    const int wv   = tid >> 6;                     // wave 0..3
    const int m0   = blockIdx.x * 32;              // block m range (32 rows)
    const int n0   = blockIdx.y * 256;             // block n range

    // W staging: thread covers 8 k-rows x 4 cols (coalesced 1KB per row)
    const int wk8 = (tid >> 6) * 8;                // 0,8,16,24
    const int wc  = (tid & 63) * 4;                // 0..252
    const float* Wstage = Wt + (size_t)wk8 * N + n0 + wc;

    // A staging: thread covers 1 float4 along k (row = tid&31, kq = tid>>5)
    const int sar = tid & 31, sakq = tid >> 5;     // row 0..31, kq 0..7
    const float* Astage = A + (size_t)(m0 + sar) * 1024 + sakq * 4;

    float acc[8][4] = {};   // single-chain accumulators

    for (int kt = 0; kt < 32; ++kt) {
        const int k0 = kt * 32;
        // global reads (issue before barrier)
        float4 wst[8];
#pragma unroll
        for (int e = 0; e < 8; ++e)
            wst[e] = *(const float4*)(Wstage + (size_t)(k0 + e) * N);
        float4 ast = *(const float4*)(Astage + k0);
        __syncthreads();             // previous tile fully consumed
#pragma unroll
        for (int e = 0; e < 8; ++e)
            *(float4*)&Ws[wk8 + e][wc] = wst[e];
        As[sakq * 4 + 0][sar] = ast.x;
        As[sakq * 4 + 1][sar] = ast.y;
        As[sakq * 4 + 2][sar] = ast.z;
        As[sakq * 4 + 3][sar] = ast.w;
        __syncthreads();

        // compute: k strictly ascending; A reads wave-uniform (broadcast)
#pragma unroll
        for (int kk = 0; kk < 32; ++kk) {
            float4 a0 = *(const float4*)&As[kk][wv * 8];       // rows 0-3
            float4 a1 = *(const float4*)&As[kk][wv * 8 + 4];   // rows 4-7
            float4 w  = *(const float4*)&Ws[kk][lane * 4];     // 4 cols
            const float a[8] = {a0.x, a0.y, a0.z, a0.w,
                                a1.x, a1.y, a1.z, a1.w};
#pragma unroll
            for (int i = 0; i < 8; ++i) {
                acc[i][0] = __builtin_fmaf(a[i], w.x, acc[i][0]);
                acc[i][1] = __builtin_fmaf(a[i], w.y, acc[i][1]);
                acc[i][2] = __builtin_fmaf(a[i], w.z, acc[i][2]);
                acc[i][3] = __builtin_fmaf(a[i], w.w, acc[i][3]);
            }
        }
    }

#pragma unroll
    for (int i = 0; i < 8; ++i) {
        float4 st = {acc[i][0], acc[i][1], acc[i][2], acc[i][3]};
        *(float4*)&C[(size_t)(m0 + wv * 8 + i) * N + n0 + lane * 4] = st;
    }
}

// ---------------------------------------------------------------------------
// fp32 LIF recurrence, numpy ufunc order, contraction off (frozen).
// In-place: Z holds GEMM output, overwritten with f32 spikes (exact 0/1).
// ---------------------------------------------------------------------------
__global__ void recur_hidden(float* __restrict__ Z, const float* __restrict__ bias) {
#pragma clang fp contract(off)
    const int idx = blockIdx.x * 256 + threadIdx.x;   // b*1024 + n
    const int n = idx & 1023, b = idx >> 10;
    const float bb = bias[n];
    float c = 0.f, v = 0.f, s = 0.f;
#pragma unroll
    for (int t = 0; t < 16; ++t) {
        const size_t p = (size_t)(b * 16 + t) * 1024 + n;
        const float z = Z[p];
        const float t1 = c * 0.5f;
        const float t2 = t1 + z;
        c = t2 + bb;
        const float u1 = v * 0.75f;
        const float u2 = u1 * (1.0f - s);
        v = u2 + c;
        s = (v > 0.5f) ? 1.0f : 0.0f;
        Z[p] = s;                                     // exact 0/1 f32
    }
}

__global__ void recur_out(const float* __restrict__ Z, const float* __restrict__ bias,
                          float* __restrict__ Out) {
#pragma clang fp contract(off)
    const int idx = blockIdx.x * 256 + threadIdx.x;   // b*512 + n
    const int n = idx & 511, b = idx >> 9;
    const float bb = bias[n];
    float c = 0.f, v = 0.f, s = 0.f, acm = 0.f;
#pragma unroll
    for (int t = 0; t < 16; ++t) {
        const float z = Z[(size_t)(b * 16 + t) * 512 + n];
        const float t1 = c * 0.5f;
        const float t2 = t1 + z;
        c = t2 + bb;
        const float u1 = v * 0.75f;
        const float u2 = u1 * (1.0f - s);
        v = u2 + c;
        s = (v > 0.5f) ? 1.0f : 0.0f;
        acm += s;                                     // small ints, exact
    }
    Out[(size_t)b * 512 + n] = acm * 0.0625f;         // exact (2^-4)
}

// ---------------------------------------------------------------------------
extern "C" void kernel_launch(void* const* d_in, const int* in_sizes, int n_in,
                              void* d_out, int out_size, void* d_ws, size_t ws_size,
                              hipStream_t stream) {
    const float* X  = (const float*)d_in[0];
    const float* W1 = (const float*)d_in[1];
    const float* b1 = (const float*)d_in[2];
    const float* W2 = (const float*)d_in[3];
    const float* b2 = (const float*)d_in[4];
    const float* Wo = (const float*)d_in[5];
    const float* bo = (const float*)d_in[6];

    char* ws = (char*)d_ws;
    float* buf0 = (float*)ws;                      // 256 MiB (A1 / Z2=S2)
    float* buf1 = (float*)(ws + (256ull << 20));   // 256 MiB (Z1=S1 / Z3)
    float* WT   = (float*)d_out;                   // 4 MiB scratch in d_out
                                                   // (8 MiB; fully rewritten
                                                   //  by recur_out at the end)

    pack_x<<<(BSZ * D_IN) / 256, 256, 0, stream>>>(X, buf0);

    // layer 1: A=buf0 -> Z=buf1, spikes in-place in buf1
    transp<<<(H1 * 1024) / 256, 256, 0, stream>>>(W1, WT, H1);
    gemm_np<<<dim3(M_ROWS / 32, H1 / 256), 256, 0, stream>>>(buf0, WT, buf1, H1);
    recur_hidden<<<(BSZ * H1) / 256, 256, 0, stream>>>(buf1, b1);
    // layer 2: A=buf1 -> Z=buf0 (overwrites A1, no longer needed)
    transp<<<(H1 * 1024) / 256, 256, 0, stream>>>(W2, WT, H1);
    gemm_np<<<dim3(M_ROWS / 32, H1 / 256), 256, 0, stream>>>(buf1, WT, buf0, H1);
    recur_hidden<<<(BSZ * H1) / 256, 256, 0, stream>>>(buf0, b2);
    // output layer: A=buf0 -> Z=buf1 [M,512]
    transp<<<(D_OUT * 1024) / 256, 256, 0, stream>>>(Wo, WT, D_OUT);
    gemm_np<<<dim3(M_ROWS / 32, D_OUT / 256), 256, 0, stream>>>(buf0, WT, buf1, D_OUT);
    recur_out<<<(BSZ * D_OUT) / 256, 256, 0, stream>>>(buf1, bo, (float*)d_out);
}

// Round 14
// 4398.066 us; speedup vs baseline: 2.0348x; 2.0348x over previous
//
#include <hip/hip_runtime.h>

// SpikeMLP — R25: global_load_lds staging (zero staging VGPRs) +
// wave-uniform A broadcast + W-only full-BW LDS, static dbuf.
// Chain contract (FROZEN, verified absmax=0.0 @ R14-R16,R18-R24):
//   per C element: acc = fma(a_k, w_k, acc), k = 0..1023 strictly
//   ascending, single accumulator, fp32, contract off. Recurrence fp32
//   ufunc order. MFMA / k-reassoc / packed-fp32 (R22 half-rate) forbidden.
// Allocator ledger: R15(68)/R18(76)/R19(84,spill)/R24(64,spill 8GB) —
//   any design needing staging regs dies at the 64-VGPR boundary.
//   R25 removes staging regs entirely: __builtin_amdgcn_global_load_lds
//   DMAs global->LDS (m97 pattern). ~50 live VGPRs. Spill-proof.
// Structure: block 32m x 256n, 4 waves (wave = 8m, lane = 4n, acc 32).
//   BK=16, static double-buffer Ws0/Ws1/As0/As1 (named arrays + manual
//   2x unroll so alias analysis can't inject vmcnt waits into compute).
//   One __syncthreads per tile (compiler emits vmcnt(0) before barrier
//   => DMA complete). LDS 36KB -> 4 blocks/CU.
//   Per kk per wave: 1 ds_read_b128 (W) + 2 broadcast reads (A) + 32 FMA.
// Predicted: VGPR ~50-64, LDS 36864, WRITE 262144 KB (jump=spill),
//   Occ ~50%, VALUBusy 82-92%, big GEMM ~1000-1350us, total ~2.7-3.2ms,
//   absmax 0.0. Flat => broadcast=12cyc, DS still binding.

typedef __attribute__((address_space(3))) unsigned int lds_u32;
typedef __attribute__((address_space(1))) const unsigned int g_u32;

__device__ __forceinline__ void glds16(const void* g, void* l) {
    __builtin_amdgcn_global_load_lds((g_u32*)g, (lds_u32*)l, 16, 0, 0);
}
__device__ __forceinline__ void glds4(const void* g, void* l) {
    __builtin_amdgcn_global_load_lds((g_u32*)g, (lds_u32*)l, 4, 0, 0);
}

static constexpr int BSZ   = 4096;
static constexpr int D_IN  = 1024;
static constexpr int H1    = 1024;
static constexpr int D_OUT = 512;
static constexpr int M_ROWS = BSZ * 16;   // 65536, m = b*16 + t

// ---------------------------------------------------------------------------
// pack X [B, D_in, T=16] f32 -> A [m = b*16 + t][d] f32 (spikes exactly 0/1)
// ---------------------------------------------------------------------------
__global__ void pack_x(const float* __restrict__ X, float* __restrict__ A) {
    const int P = blockIdx.x * 256 + threadIdx.x;     // P = b*1024 + d
    const int b = P >> 10, d = P & 1023;
    const float4* xp = (const float4*)(X + (size_t)P * 16);
    float4 x0 = xp[0], x1 = xp[1], x2 = xp[2], x3 = xp[3];
    const float v[16] = {x0.x, x0.y, x0.z, x0.w, x1.x, x1.y, x1.z, x1.w,
                         x2.x, x2.y, x2.z, x2.w, x3.x, x3.y, x3.z, x3.w};
#pragma unroll
    for (int t = 0; t < 16; ++t)
        A[((size_t)(b * 16 + t)) * 1024 + d] = v[t];
}

// ---------------------------------------------------------------------------
// W [R][1024] -> Wt [1024][R]  (pure copy, bit-exact)
// ---------------------------------------------------------------------------
__global__ void transp(const float* __restrict__ W, float* __restrict__ Wt,
                       int R) {
    const int P = blockIdx.x * 256 + threadIdx.x;   // n*1024 + k
    const int k = P & 1023, n = P >> 10;
    Wt[(size_t)k * R + n] = W[P];
}

// ---------------------------------------------------------------------------
// GEMM, reference fp32 chain. C[m][n] = A[m,:] . W[n,:], K = 1024.
// Block: 32 m (4 waves x 8 rows) x 256 n. Lane tile 8m x 4n (32 acc).
// BK = 16, static double-buffer, global_load_lds staging.
// Single ascending accumulator over full K (frozen chain).
// ---------------------------------------------------------------------------
__global__ __launch_bounds__(256) void gemm_np(
    const float* __restrict__ A,    // [M, 1024] f32 spikes (exactly 0/1)
    const float* __restrict__ Wt,   // [1024, N] f32 (k-major transpose of W)
    float* __restrict__ C,          // [M, N] fp32
    int N) {
#pragma clang fp contract(off)
    __shared__ float Ws0[16][256];  // 16 KB  [kk][n]
    __shared__ float Ws1[16][256];  // 16 KB
    __shared__ float As0[16][32];   //  2 KB  [kk][m]
    __shared__ float As1[16][32];   //  2 KB

    const int tid  = threadIdx.x;
    const int lane = tid & 63;
    const int wv   = tid >> 6;                     // wave 0..3
    const int m0   = blockIdx.x * 32;
    const int n0   = blockIdx.y * 256;

    const int wv4 = wv * 4, wv2 = wv * 2, wv8 = wv * 8, lane4 = lane * 4;

    // DMA source bases
    const float* wsrc = Wt + n0 + lane4;                       // + (k)*N
    const float* asrc = A + (size_t)(m0 + (lane & 31)) * 1024  // + k
                          + (lane >> 5);

    float acc[8][4] = {};   // single-chain accumulators

#define DMA_TILE(BW, BA, K0) do {                                              \
    _Pragma("unroll")                                                          \
    for (int r = 0; r < 4; ++r)                                                \
        glds16(wsrc + (size_t)((K0) + wv4 + r) * N, &BW[wv4 + r][0]);          \
    _Pragma("unroll")                                                          \
    for (int p = 0; p < 2; ++p)                                                \
        glds4(asrc + (K0) + 2 * (wv2 + p), &BA[2 * (wv2 + p)][0]);             \
} while (0)

#define COMP_TILE(BW, BA) do {                                                 \
    _Pragma("unroll")                                                          \
    for (int kk = 0; kk < 16; ++kk) {                                          \
        float4 a0 = *(const float4*)&BA[kk][wv8];                              \
        float4 a1 = *(const float4*)&BA[kk][wv8 + 4];                          \
        float4 w  = *(const float4*)&BW[kk][lane4];                            \
        const float a[8] = {a0.x, a0.y, a0.z, a0.w, a1.x, a1.y, a1.z, a1.w};   \
        _Pragma("unroll")                                                      \
        for (int i = 0; i < 8; ++i) {                                          \
            acc[i][0] = __builtin_fmaf(a[i], w.x, acc[i][0]);                  \
            acc[i][1] = __builtin_fmaf(a[i], w.y, acc[i][1]);                  \
            acc[i][2] = __builtin_fmaf(a[i], w.z, acc[i][2]);                  \
            acc[i][3] = __builtin_fmaf(a[i], w.w, acc[i][3]);                  \
        }                                                                      \
    }                                                                          \
} while (0)

    // prologue: tile 0 -> buf0
    DMA_TILE(Ws0, As0, 0);

#pragma unroll 1
    for (int kt = 0; kt < 64; kt += 2) {
        __syncthreads();                       // buf0 DMA done; buf1 free
        DMA_TILE(Ws1, As1, (kt + 1) * 16);     // tile kt+1 -> buf1
        COMP_TILE(Ws0, As0);                   // tile kt (k ascending)
        __syncthreads();                       // buf1 DMA done; buf0 free
        const int k2 = (kt + 2 < 64) ? (kt + 2) * 16 : 63 * 16;  // clamp
        DMA_TILE(Ws0, As0, k2);                // tile kt+2 -> buf0
        COMP_TILE(Ws1, As1);                   // tile kt+1
    }
#undef DMA_TILE
#undef COMP_TILE

#pragma unroll
    for (int i = 0; i < 8; ++i) {
        float4 st = {acc[i][0], acc[i][1], acc[i][2], acc[i][3]};
        *(float4*)&C[(size_t)(m0 + wv8 + i) * N + n0 + lane4] = st;
    }
}

// ---------------------------------------------------------------------------
// fp32 LIF recurrence, numpy ufunc order, contraction off (frozen).
// In-place: Z holds GEMM output, overwritten with f32 spikes (exact 0/1).
// ---------------------------------------------------------------------------
__global__ void recur_hidden(float* __restrict__ Z, const float* __restrict__ bias) {
#pragma clang fp contract(off)
    const int idx = blockIdx.x * 256 + threadIdx.x;   // b*1024 + n
    const int n = idx & 1023, b = idx >> 10;
    const float bb = bias[n];
    float c = 0.f, v = 0.f, s = 0.f;
#pragma unroll
    for (int t = 0; t < 16; ++t) {
        const size_t p = (size_t)(b * 16 + t) * 1024 + n;
        const float z = Z[p];
        const float t1 = c * 0.5f;
        const float t2 = t1 + z;
        c = t2 + bb;
        const float u1 = v * 0.75f;
        const float u2 = u1 * (1.0f - s);
        v = u2 + c;
        s = (v > 0.5f) ? 1.0f : 0.0f;
        Z[p] = s;                                     // exact 0/1 f32
    }
}

__global__ void recur_out(const float* __restrict__ Z, const float* __restrict__ bias,
                          float* __restrict__ Out) {
#pragma clang fp contract(off)
    const int idx = blockIdx.x * 256 + threadIdx.x;   // b*512 + n
    const int n = idx & 511, b = idx >> 9;
    const float bb = bias[n];
    float c = 0.f, v = 0.f, s = 0.f, acm = 0.f;
#pragma unroll
    for (int t = 0; t < 16; ++t) {
        const float z = Z[(size_t)(b * 16 + t) * 512 + n];
        const float t1 = c * 0.5f;
        const float t2 = t1 + z;
        c = t2 + bb;
        const float u1 = v * 0.75f;
        const float u2 = u1 * (1.0f - s);
        v = u2 + c;
        s = (v > 0.5f) ? 1.0f : 0.0f;
        acm += s;                                     // small ints, exact
    }
    Out[(size_t)b * 512 + n] = acm * 0.0625f;         // exact (2^-4)
}

// ---------------------------------------------------------------------------
extern "C" void kernel_launch(void* const* d_in, const int* in_sizes, int n_in,
                              void* d_out, int out_size, void* d_ws, size_t ws_size,
                              hipStream_t stream) {
    const float* X  = (const float*)d_in[0];
    const float* W1 = (const float*)d_in[1];
    const float* b1 = (const float*)d_in[2];
    const float* W2 = (const float*)d_in[3];
    const float* b2 = (const float*)d_in[4];
    const float* Wo = (const float*)d_in[5];
    const float* bo = (const float*)d_in[6];

    char* ws = (char*)d_ws;
    float* buf0 = (float*)ws;                      // 256 MiB (A1 / Z2=S2)
    float* buf1 = (float*)(ws + (256ull << 20));   // 256 MiB (Z1=S1 / Z3)
    float* WT   = (float*)d_out;                   // 4 MiB scratch in d_out
                                                   // (8 MiB; fully rewritten
                                                   //  by recur_out at the end)

    pack_x<<<(BSZ * D_IN) / 256, 256, 0, stream>>>(X, buf0);

    // layer 1: A=buf0 -> Z=buf1, spikes in-place in buf1
    transp<<<(H1 * 1024) / 256, 256, 0, stream>>>(W1, WT, H1);
    gemm_np<<<dim3(M_ROWS / 32, H1 / 256), 256, 0, stream>>>(buf0, WT, buf1, H1);
    recur_hidden<<<(BSZ * H1) / 256, 256, 0, stream>>>(buf1, b1);
    // layer 2: A=buf1 -> Z=buf0 (overwrites A1, no longer needed)
    transp<<<(H1 * 1024) / 256, 256, 0, stream>>>(W2, WT, H1);
    gemm_np<<<dim3(M_ROWS / 32, H1 / 256), 256, 0, stream>>>(buf1, WT, buf0, H1);
    recur_hidden<<<(BSZ * H1) / 256, 256, 0, stream>>>(buf0, b2);
    // output layer: A=buf0 -> Z=buf1 [M,512]
    transp<<<(D_OUT * 1024) / 256, 256, 0, stream>>>(Wo, WT, D_OUT);
    gemm_np<<<dim3(M_ROWS / 32, D_OUT / 256), 256, 0, stream>>>(buf0, WT, buf1, D_OUT);
    recur_out<<<(BSZ * D_OUT) / 256, 256, 0, stream>>>(buf1, bo, (float*)d_out);
}

// Round 15
// 4382.269 us; speedup vs baseline: 2.0422x; 1.0036x over previous
//
#include <hip/hip_runtime.h>

// SpikeMLP — R26: 16x8 per-thread tile (DS-ratio fix) + padded/swizzled LDS.
// Chain contract (FROZEN, verified absmax=0.0 @ R14-R16,R18-R25):
//   per C element: acc = fma(a_k, w_k, acc), k = 0..1023 strictly
//   ascending, single accumulator, fp32, contract off. Recurrence fp32
//   ufunc order. MFMA / k-reassoc / packed-fp32 (R22: half-rate) forbidden.
// DS-wall model (now measured 5 ways): ~12 cyc per wave-b128 per CU,
//   NO broadcast discount (R25). Per-thread tile RxC reads (R+C)x4 B per
//   RxC FMAs -> DS-over factor = 6(R+C)/(RC). 8x8 = 1.5x (the 1600us
//   plateau). 16x8 = 1.13x -> expected ~1.3x GEMM speedup.
// VGPR: acc 128 + operands 64 + addr ~15 = 207 < 256 cap @ (256,2) --
//   inside cap (R19/R24 spilled because need EXCEEDED cap).
// Banks (32-float rows lose the free 128-wide layout):
//   As stride 33 (padded): reads 16-row-apart = 2-way free; staging
//   writes spread by odd stride (33 = 1 mod 32). Ws stride 32 + chunk
//   XOR swizzle (chunk ^= (n>>3)&7): tx-lanes spread over 8 bank groups
//   2-way free; both write and read sides apply the same XOR (reg-staged
//   ds_write — no global_load_lds linearity constraint).
// Predicted: VGPR ~200-240, LDS 50176, WRITE 262144 KB (jump=spill),
//   BANK_CONFLICT ~0, Occ ~25%, VALUBusy 80-88%, big GEMM ~1100-1300us,
//   total ~2.9-3.2ms, absmax 0.0.

typedef float floatx4 __attribute__((ext_vector_type(4)));

static constexpr int BSZ   = 4096;
static constexpr int D_IN  = 1024;
static constexpr int H1    = 1024;
static constexpr int D_OUT = 512;
static constexpr int M_ROWS = BSZ * 16;   // 65536, m = b*16 + t

// ---------------------------------------------------------------------------
// pack X [B, D_in, T=16] f32 -> A [m = b*16 + t][d] f32 (spikes exactly 0/1)
// ---------------------------------------------------------------------------
__global__ void pack_x(const float* __restrict__ X, float* __restrict__ A) {
    const int P = blockIdx.x * 256 + threadIdx.x;     // P = b*1024 + d
    const int b = P >> 10, d = P & 1023;
    const float4* xp = (const float4*)(X + (size_t)P * 16);
    float4 x0 = xp[0], x1 = xp[1], x2 = xp[2], x3 = xp[3];
    const float v[16] = {x0.x, x0.y, x0.z, x0.w, x1.x, x1.y, x1.z, x1.w,
                         x2.x, x2.y, x2.z, x2.w, x3.x, x3.y, x3.z, x3.w};
#pragma unroll
    for (int t = 0; t < 16; ++t)
        A[((size_t)(b * 16 + t)) * 1024 + d] = v[t];
}

// ---------------------------------------------------------------------------
// GEMM, reference fp32 chain. C[m][n] = A[m,:] . W[n,:], K = 1024.
// Block 256(M) x 128(N), 256 threads, 16x8 per thread. BK = 32.
// LDS: As[256][33] (padded), Ws[128][32] (chunk-swizzled). Single buffer,
// 2 barriers/tile (R21 cadence). Single ascending accumulator (frozen).
// Thread (tx,ty): rows ty*16..+15, cols tx*8..+7.
// ---------------------------------------------------------------------------
__global__ __launch_bounds__(256, 2) void gemm_np(
    const float* __restrict__ A,    // [M, 1024] f32 spikes (exactly 0/1)
    const float* __restrict__ W,    // [N, 1024] f32 weights (raw input)
    float* __restrict__ C,          // [M, N] fp32
    int N) {
#pragma clang fp contract(off)
    __shared__ float As[256 * 33];  // 33792 B, row stride 33 (pad)
    __shared__ float Ws[128 * 32];  // 16384 B, chunk-swizzled

    const int tid = threadIdx.x;
    const int tx = tid & 15;        // col group: cols tx*8 .. +7
    const int ty = tid >> 4;        // row group: rows ty*16 .. +15
    const int m0 = blockIdx.x * 256, n0 = blockIdx.y * 128;

    // staging assignments
    const float* Ag = A + (size_t)(m0 + tid) * 1024;         // 1 row/thread
    const int wn = tid & 127, wq0 = (tid >> 7) * 4;          // W row, chunks
    const float* Wg = W + (size_t)(n0 + wn) * 1024 + wq0 * 4;
    const int wswz = (wn >> 3) & 7;

    float acc[16][8] = {};   // single-chain accumulators

    for (int kt = 0; kt < 32; ++kt) {
        const int k0 = kt * 32;
        // global reads (issue before barrier; R21 cadence)
        floatx4 av[8], wv[4];
#pragma unroll
        for (int c = 0; c < 8; ++c)
            av[c] = *(const floatx4*)(Ag + k0 + c * 4);
#pragma unroll
        for (int q = 0; q < 4; ++q)
            wv[q] = *(const floatx4*)(Wg + k0 + q * 4);
        __syncthreads();             // previous tile fully consumed
#pragma unroll
        for (int c = 0; c < 8; ++c)
            *(floatx4*)&As[tid * 33 + c * 4] = av[c];        // padded, linear
#pragma unroll
        for (int q = 0; q < 4; ++q)
            *(floatx4*)&Ws[wn * 32 + (((wq0 + q) ^ wswz) * 4)] = wv[q];
        __syncthreads();

        // compute: kq quads ascending, kk ascending within quad (frozen)
#pragma unroll
        for (int kq = 0; kq < 8; ++kq) {
            const int wch = (kq ^ (tx & 7)) * 4;   // W swizzled chunk
            const int ach = kq * 4;                // A linear chunk
            floatx4 w4[8], a4[8];
#pragma unroll
            for (int j = 0; j < 8; ++j)
                w4[j] = *(const floatx4*)&Ws[(tx * 8 + j) * 32 + wch];
#pragma unroll
            for (int i = 0; i < 8; ++i)
                a4[i] = *(const floatx4*)&As[(ty * 16 + i) * 33 + ach];
#pragma unroll
            for (int kk = 0; kk < 4; ++kk)         // strictly k-ascending
#pragma unroll
                for (int i = 0; i < 8; ++i)
#pragma unroll
                    for (int j = 0; j < 8; ++j)
                        acc[i][j] = __builtin_fmaf(a4[i][kk], w4[j][kk], acc[i][j]);
#pragma unroll
            for (int i = 0; i < 8; ++i)            // rows 8..15, same quad
                a4[i] = *(const floatx4*)&As[(ty * 16 + 8 + i) * 33 + ach];
#pragma unroll
            for (int kk = 0; kk < 4; ++kk)
#pragma unroll
                for (int i = 0; i < 8; ++i)
#pragma unroll
                    for (int j = 0; j < 8; ++j)
                        acc[8 + i][j] = __builtin_fmaf(a4[i][kk], w4[j][kk], acc[8 + i][j]);
        }
    }

#pragma unroll
    for (int i = 0; i < 16; ++i) {
        floatx4 s0 = {acc[i][0], acc[i][1], acc[i][2], acc[i][3]};
        floatx4 s1 = {acc[i][4], acc[i][5], acc[i][6], acc[i][7]};
        float* cp = C + (size_t)(m0 + ty * 16 + i) * N + n0 + tx * 8;
        *(floatx4*)cp       = s0;
        *(floatx4*)(cp + 4) = s1;
    }
}

// ---------------------------------------------------------------------------
// fp32 LIF recurrence, numpy ufunc order, contraction off (frozen).
// In-place: Z holds GEMM output, overwritten with f32 spikes (exact 0/1).
// ---------------------------------------------------------------------------
__global__ void recur_hidden(float* __restrict__ Z, const float* __restrict__ bias) {
#pragma clang fp contract(off)
    const int idx = blockIdx.x * 256 + threadIdx.x;   // b*1024 + n
    const int n = idx & 1023, b = idx >> 10;
    const float bb = bias[n];
    float c = 0.f, v = 0.f, s = 0.f;
#pragma unroll
    for (int t = 0; t < 16; ++t) {
        const size_t p = (size_t)(b * 16 + t) * 1024 + n;
        const float z = Z[p];
        const float t1 = c * 0.5f;
        const float t2 = t1 + z;
        c = t2 + bb;
        const float u1 = v * 0.75f;
        const float u2 = u1 * (1.0f - s);
        v = u2 + c;
        s = (v > 0.5f) ? 1.0f : 0.0f;
        Z[p] = s;                                     // exact 0/1 f32
    }
}

__global__ void recur_out(const float* __restrict__ Z, const float* __restrict__ bias,
                          float* __restrict__ Out) {
#pragma clang fp contract(off)
    const int idx = blockIdx.x * 256 + threadIdx.x;   // b*512 + n
    const int n = idx & 511, b = idx >> 9;
    const float bb = bias[n];
    float c = 0.f, v = 0.f, s = 0.f, acm = 0.f;
#pragma unroll
    for (int t = 0; t < 16; ++t) {
        const float z = Z[(size_t)(b * 16 + t) * 512 + n];
        const float t1 = c * 0.5f;
        const float t2 = t1 + z;
        c = t2 + bb;
        const float u1 = v * 0.75f;
        const float u2 = u1 * (1.0f - s);
        v = u2 + c;
        s = (v > 0.5f) ? 1.0f : 0.0f;
        acm += s;                                     // small ints, exact
    }
    Out[(size_t)b * 512 + n] = acm * 0.0625f;         // exact (2^-4)
}

// ---------------------------------------------------------------------------
extern "C" void kernel_launch(void* const* d_in, const int* in_sizes, int n_in,
                              void* d_out, int out_size, void* d_ws, size_t ws_size,
                              hipStream_t stream) {
    const float* X  = (const float*)d_in[0];
    const float* W1 = (const float*)d_in[1];
    const float* b1 = (const float*)d_in[2];
    const float* W2 = (const float*)d_in[3];
    const float* b2 = (const float*)d_in[4];
    const float* Wo = (const float*)d_in[5];
    const float* bo = (const float*)d_in[6];

    char* ws = (char*)d_ws;
    float* buf0 = (float*)ws;                      // 256 MiB (A1 / Z2=S2)
    float* buf1 = (float*)(ws + (256ull << 20));   // 256 MiB (Z1=S1 / Z3)

    pack_x<<<(BSZ * D_IN) / 256, 256, 0, stream>>>(X, buf0);

    // layer 1: A=buf0 -> Z=buf1, spikes in-place in buf1
    gemm_np<<<dim3(M_ROWS / 256, H1 / 128), 256, 0, stream>>>(buf0, W1, buf1, H1);
    recur_hidden<<<(BSZ * H1) / 256, 256, 0, stream>>>(buf1, b1);
    // layer 2: A=buf1 -> Z=buf0 (overwrites A1, no longer needed)
    gemm_np<<<dim3(M_ROWS / 256, H1 / 128), 256, 0, stream>>>(buf1, W2, buf0, H1);
    recur_hidden<<<(BSZ * H1) / 256, 256, 0, stream>>>(buf0, b2);
    // output layer: A=buf0 -> Z=buf1 [M,512]
    gemm_np<<<dim3(M_ROWS / 256, D_OUT / 128), 256, 0, stream>>>(buf0, Wo, buf1, D_OUT);
    recur_out<<<(BSZ * D_OUT) / 256, 256, 0, stream>>>(buf1, bo, (float*)d_out);
}